// Round 6
// baseline (387.918 us; speedup 1.0000x reference)
//
#include <hip/hip_runtime.h>
#include <hip/hip_cooperative_groups.h>

namespace cg = cooperative_groups;

#define LN_EPS 1e-5f

// ---------------- Fused cooperative kernel ----------------
// Phase A: per-node table[n] = {S, Q, A_lo, A_hi}
//   (32 lanes/node, 2 nodes/wave, grid-stride over nodes)
// grid.sync() with device-scope fences (cross-XCD table visibility)
// Phase B: per-edge score, 2 edges/thread grid-stride:
//   s=S[s]+S[d], q=Q[s]+Q[d], a=A_lo[s]+A_hi[d]
//   score = rs*(a - mu*sum_gw) + (sum(beta*W)+b)
__global__ __launch_bounds__(256)
void fused_edge_ln_kernel(const float* __restrict__ h,
                          const int* __restrict__ src,
                          const int* __restrict__ dst,
                          const float* __restrict__ gamma,
                          const float* __restrict__ beta,
                          const float* __restrict__ W,
                          const float* __restrict__ bias,
                          float4* __restrict__ table,
                          float* __restrict__ out,
                          int N, int E)
{
    const int tid  = threadIdx.x;
    const int lane = tid & 63;
    const int l    = lane & 31;   // lane within node
    const int half = lane >> 5;   // node index within the wave's pair

    const float4* g4 = (const float4*)gamma;
    const float4* b4 = (const float4*)beta;
    const float4* w4 = (const float4*)W;

    // Constants in-register (every wave computes them; L1-hit loads):
    float4 gg = g4[lane], ww = w4[lane], bb = b4[lane];
    float gwsum = (gg.x * ww.x + gg.y * ww.y) + (gg.z * ww.z + gg.w * ww.w);
    float bwsum = (bb.x * ww.x + bb.y * ww.y) + (bb.z * ww.z + bb.w * ww.w);
#pragma unroll
    for (int m = 1; m < 64; m <<= 1) {
        gwsum += __shfl_xor(gwsum, m, 64);
        bwsum += __shfl_xor(bwsum, m, 64);
    }
    const float sum_gw = gwsum;
    const float cbeta  = bwsum + bias[0];
    const float inv_d  = 1.0f / 256.0f;

    // gamma*W fragments for this lane's feature slice (lo/hi half)
    float4 glo = g4[l],      wlo = w4[l];
    float4 ghi = g4[l + 32], whi = w4[l + 32];
    float4 gwlo = {glo.x * wlo.x, glo.y * wlo.y, glo.z * wlo.z, glo.w * wlo.w};
    float4 gwhi = {ghi.x * whi.x, ghi.y * whi.y, ghi.z * whi.z, ghi.w * whi.w};

    // ---- Phase A: node table ----
    const int waveId = (blockIdx.x * blockDim.x + tid) >> 6;
    const int nWaves = (gridDim.x * blockDim.x) >> 6;

    for (int node = waveId * 2 + half; node < N; node += nWaves * 2) {
        const float4* row = (const float4*)h + (size_t)node * 32;
        float4 v = row[l];

        float s = (v.x + v.y) + (v.z + v.w);
        float q = fmaf(v.x, v.x, fmaf(v.y, v.y, fmaf(v.z, v.z, v.w * v.w)));
        float alo = fmaf(v.x, gwlo.x, fmaf(v.y, gwlo.y, fmaf(v.z, gwlo.z, v.w * gwlo.w)));
        float ahi = fmaf(v.x, gwhi.x, fmaf(v.y, gwhi.y, fmaf(v.z, gwhi.z, v.w * gwhi.w)));

#pragma unroll
        for (int m = 1; m < 32; m <<= 1) {
            s   += __shfl_xor(s,   m, 64);
            q   += __shfl_xor(q,   m, 64);
            alo += __shfl_xor(alo, m, 64);
            ahi += __shfl_xor(ahi, m, 64);
        }
        if (l == 0) table[node] = make_float4(s, q, alo, ahi);
    }

    // Device-scope visibility across XCDs, then grid-wide barrier.
    __threadfence();
    cg::this_grid().sync();
    __threadfence();

    // ---- Phase B: edge scoring, 2 edges/thread ----
    const int t  = blockIdx.x * blockDim.x + tid;
    const int nT = gridDim.x * blockDim.x;
    const int nPairs = E >> 1;

    for (int p = t; p < nPairs; p += nT) {
        const int e0 = p * 2;
        int2 s2 = *(const int2*)(src + e0);
        int2 d2 = *(const int2*)(dst + e0);
        float4 ts0 = table[s2.x];
        float4 td0 = table[d2.x];
        float4 ts1 = table[s2.y];
        float4 td1 = table[d2.y];

        float s0 = ts0.x + td0.x, q0 = ts0.y + td0.y, a0 = ts0.z + td0.w;
        float s1 = ts1.x + td1.x, q1 = ts1.y + td1.y, a1 = ts1.z + td1.w;

        float mu0  = s0 * inv_d;
        float var0 = fmaf(-mu0, mu0, q0 * inv_d);
        float rs0  = rsqrtf(var0 + LN_EPS);
        float mu1  = s1 * inv_d;
        float var1 = fmaf(-mu1, mu1, q1 * inv_d);
        float rs1  = rsqrtf(var1 + LN_EPS);

        float2 r;
        r.x = fmaf(rs0, fmaf(-mu0, sum_gw, a0), cbeta);
        r.y = fmaf(rs1, fmaf(-mu1, sum_gw, a1), cbeta);
        *(float2*)(out + e0) = r;
    }
    if ((E & 1) && t == 0) {
        const int e = E - 1;
        float4 ts = table[src[e]];
        float4 td = table[dst[e]];
        float s = ts.x + td.x, q = ts.y + td.y, a = ts.z + td.w;
        float mu  = s * inv_d;
        float var = fmaf(-mu, mu, q * inv_d);
        float rs  = rsqrtf(var + LN_EPS);
        out[e] = fmaf(rs, fmaf(-mu, sum_gw, a), cbeta);
    }
}

// ---------------- Two-kernel path (R2-proven) as fallback ----------------
__global__ __launch_bounds__(256)
void node_precompute_kernel(const float* __restrict__ h,
                            const float* __restrict__ gamma,
                            const float* __restrict__ beta,
                            const float* __restrict__ W,
                            const float* __restrict__ bias,
                            float4* __restrict__ table,
                            float* __restrict__ consts,
                            int N)
{
    const int tid  = threadIdx.x;
    const int lane = tid & 63;
    const int l    = lane & 31;
    const int half = lane >> 5;

    const float4* g4 = (const float4*)gamma;
    const float4* b4 = (const float4*)beta;
    const float4* w4 = (const float4*)W;

    if (blockIdx.x == 0 && tid < 64) {
        float4 gg = g4[tid], ww = w4[tid], bb = b4[tid];
        float gwsum = (gg.x * ww.x + gg.y * ww.y) + (gg.z * ww.z + gg.w * ww.w);
        float bwsum = (bb.x * ww.x + bb.y * ww.y) + (bb.z * ww.z + bb.w * ww.w);
#pragma unroll
        for (int m = 1; m < 64; m <<= 1) {
            gwsum += __shfl_xor(gwsum, m, 64);
            bwsum += __shfl_xor(bwsum, m, 64);
        }
        if (tid == 0) { consts[0] = gwsum; consts[1] = bwsum + bias[0]; }
    }

    float4 glo = g4[l],      wlo = w4[l];
    float4 ghi = g4[l + 32], whi = w4[l + 32];
    float4 gwlo = {glo.x * wlo.x, glo.y * wlo.y, glo.z * wlo.z, glo.w * wlo.w};
    float4 gwhi = {ghi.x * whi.x, ghi.y * whi.y, ghi.z * whi.z, ghi.w * whi.w};

    const int waveInBlock = tid >> 6;
    const int node = (blockIdx.x * 4 + waveInBlock) * 2 + half;
    if (node >= N) return;

    const float4* row = (const float4*)h + (size_t)node * 32;
    float4 v = row[l];

    float s = (v.x + v.y) + (v.z + v.w);
    float q = fmaf(v.x, v.x, fmaf(v.y, v.y, fmaf(v.z, v.z, v.w * v.w)));
    float alo = fmaf(v.x, gwlo.x, fmaf(v.y, gwlo.y, fmaf(v.z, gwlo.z, v.w * gwlo.w)));
    float ahi = fmaf(v.x, gwhi.x, fmaf(v.y, gwhi.y, fmaf(v.z, gwhi.z, v.w * gwhi.w)));

#pragma unroll
    for (int m = 1; m < 32; m <<= 1) {
        s   += __shfl_xor(s,   m, 64);
        q   += __shfl_xor(q,   m, 64);
        alo += __shfl_xor(alo, m, 64);
        ahi += __shfl_xor(ahi, m, 64);
    }
    if (l == 0) table[node] = make_float4(s, q, alo, ahi);
}

__global__ __launch_bounds__(256)
void edge_score2_kernel(const int* __restrict__ src,
                        const int* __restrict__ dst,
                        const float4* __restrict__ table,
                        const float* __restrict__ consts,
                        float* __restrict__ out,
                        int E)
{
    const int t = blockIdx.x * blockDim.x + threadIdx.x;
    const int e0 = t * 2;
    if (e0 >= E) return;

    const float sum_gw = consts[0];
    const float cbeta  = consts[1];
    const float inv_d  = 1.0f / 256.0f;

    if (e0 + 1 < E) {
        int2 s2 = *(const int2*)(src + e0);
        int2 d2 = *(const int2*)(dst + e0);
        float4 ts0 = table[s2.x];
        float4 td0 = table[d2.x];
        float4 ts1 = table[s2.y];
        float4 td1 = table[d2.y];

        float s0 = ts0.x + td0.x, q0 = ts0.y + td0.y, a0 = ts0.z + td0.w;
        float s1 = ts1.x + td1.x, q1 = ts1.y + td1.y, a1 = ts1.z + td1.w;

        float mu0  = s0 * inv_d;
        float var0 = fmaf(-mu0, mu0, q0 * inv_d);
        float rs0  = rsqrtf(var0 + LN_EPS);
        float mu1  = s1 * inv_d;
        float var1 = fmaf(-mu1, mu1, q1 * inv_d);
        float rs1  = rsqrtf(var1 + LN_EPS);

        float2 r;
        r.x = fmaf(rs0, fmaf(-mu0, sum_gw, a0), cbeta);
        r.y = fmaf(rs1, fmaf(-mu1, sum_gw, a1), cbeta);
        *(float2*)(out + e0) = r;
    } else {
        float4 ts = table[src[e0]];
        float4 td = table[dst[e0]];
        float s = ts.x + td.x;
        float q = ts.y + td.y;
        float a = ts.z + td.w;
        float mu  = s * inv_d;
        float var = fmaf(-mu, mu, q * inv_d);
        float rs  = rsqrtf(var + LN_EPS);
        out[e0] = fmaf(rs, fmaf(-mu, sum_gw, a), cbeta);
    }
}

// ---------------- Last-resort fallback (single-pass gather) ----------------
__global__ __launch_bounds__(256)
void edge_ln_score_fallback(const float* __restrict__ h,
                            const int* __restrict__ src,
                            const int* __restrict__ dst,
                            const float* __restrict__ gamma,
                            const float* __restrict__ beta,
                            const float* __restrict__ W,
                            const float* __restrict__ bias,
                            float* __restrict__ out,
                            int E)
{
    const int tid  = threadIdx.x;
    const int lane = tid & 63;
    const int l    = lane & 15;
    const int grp  = lane >> 4;

    const int waveInBlock   = tid >> 6;
    const int wavesPerBlock = blockDim.x >> 6;
    const int gwave      = blockIdx.x * wavesPerBlock + waveInBlock;
    const int waveStride = gridDim.x * wavesPerBlock;

    const float4* g4 = (const float4*)gamma;
    const float4* b4 = (const float4*)beta;
    const float4* w4 = (const float4*)W;

    float4 gw[4];
    float gwsum = 0.0f, bwsum = 0.0f;
#pragma unroll
    for (int k = 0; k < 4; ++k) {
        float4 gg = g4[l + 16 * k];
        float4 ww = w4[l + 16 * k];
        float4 bb = b4[l + 16 * k];
        float4 r;
        r.x = gg.x * ww.x; r.y = gg.y * ww.y;
        r.z = gg.z * ww.z; r.w = gg.w * ww.w;
        gw[k] = r;
        gwsum += (r.x + r.y) + (r.z + r.w);
        bwsum += (bb.x * ww.x + bb.y * ww.y) + (bb.z * ww.z + bb.w * ww.w);
    }
#pragma unroll
    for (int m = 1; m < 64; m <<= 1) {
        gwsum += __shfl_xor(gwsum, m, 64);
        bwsum += __shfl_xor(bwsum, m, 64);
    }
    const float sum_gw = 0.25f * gwsum;
    const float cbeta  = fmaf(0.25f, bwsum, bias[0]);
    const float inv_d  = 1.0f / 256.0f;

    for (int base = gwave * 4; base < E; base += waveStride * 4) {
        int e  = base + grp;
        int ec = (e < E) ? e : (E - 1);
        int si = src[ec];
        int di = dst[ec];
        const float4* hs = (const float4*)h + si * 32;
        const float4* hd = (const float4*)h + di * 32;
        float4 v0 = hs[l];
        float4 v1 = hs[l + 16];
        float4 v2 = hd[l];
        float4 v3 = hd[l + 16];

        float s = ((v0.x + v0.y) + (v0.z + v0.w))
                + ((v1.x + v1.y) + (v1.z + v1.w))
                + ((v2.x + v2.y) + (v2.z + v2.w))
                + ((v3.x + v3.y) + (v3.z + v3.w));
        float q = 0.0f;
        q = fmaf(v0.x, v0.x, q); q = fmaf(v0.y, v0.y, q);
        q = fmaf(v0.z, v0.z, q); q = fmaf(v0.w, v0.w, q);
        q = fmaf(v1.x, v1.x, q); q = fmaf(v1.y, v1.y, q);
        q = fmaf(v1.z, v1.z, q); q = fmaf(v1.w, v1.w, q);
        q = fmaf(v2.x, v2.x, q); q = fmaf(v2.y, v2.y, q);
        q = fmaf(v2.z, v2.z, q); q = fmaf(v2.w, v2.w, q);
        q = fmaf(v3.x, v3.x, q); q = fmaf(v3.y, v3.y, q);
        q = fmaf(v3.z, v3.z, q); q = fmaf(v3.w, v3.w, q);
        float a = 0.0f;
        a = fmaf(v0.x, gw[0].x, a); a = fmaf(v0.y, gw[0].y, a);
        a = fmaf(v0.z, gw[0].z, a); a = fmaf(v0.w, gw[0].w, a);
        a = fmaf(v1.x, gw[1].x, a); a = fmaf(v1.y, gw[1].y, a);
        a = fmaf(v1.z, gw[1].z, a); a = fmaf(v1.w, gw[1].w, a);
        a = fmaf(v2.x, gw[2].x, a); a = fmaf(v2.y, gw[2].y, a);
        a = fmaf(v2.z, gw[2].z, a); a = fmaf(v2.w, gw[2].w, a);
        a = fmaf(v3.x, gw[3].x, a); a = fmaf(v3.y, gw[3].y, a);
        a = fmaf(v3.z, gw[3].z, a); a = fmaf(v3.w, gw[3].w, a);
#pragma unroll
        for (int m = 1; m < 16; m <<= 1) {
            s += __shfl_xor(s, m, 64);
            q += __shfl_xor(q, m, 64);
            a += __shfl_xor(a, m, 64);
        }
        float mu    = s * inv_d;
        float var   = fmaf(-mu, mu, q * inv_d);
        float rs    = rsqrtf(var + LN_EPS);
        float score = fmaf(rs, fmaf(-mu, sum_gw, a), cbeta);
        if (l == 0 && e < E) out[e] = score;
    }
}

extern "C" void kernel_launch(void* const* d_in, const int* in_sizes, int n_in,
                              void* d_out, int out_size, void* d_ws, size_t ws_size,
                              hipStream_t stream) {
    const float* h     = (const float*)d_in[0];
    const int*   src   = (const int*)d_in[1];
    const int*   dst   = (const int*)d_in[2];
    const float* gamma = (const float*)d_in[3];
    const float* beta  = (const float*)d_in[4];
    const float* W     = (const float*)d_in[5];
    const float* b     = (const float*)d_in[6];
    float* out = (float*)d_out;
    const int E = in_sizes[1];
    const int N = in_sizes[0] / 128;

    const size_t ws_needed = (size_t)N * 16 + 16;
    if (ws_size < ws_needed) {
        hipLaunchKernelGGL(edge_ln_score_fallback, dim3(2048), dim3(256), 0, stream,
                           h, src, dst, gamma, beta, W, b, out, E);
        return;
    }

    float4* table  = (float4*)d_ws;
    float*  consts = (float*)((char*)d_ws + (size_t)N * 16);

    // Cooperative fused path: 1024 blocks x 256 threads (4 blocks/CU,
    // guaranteed co-resident at our 32-48 VGPR footprint).
    void* args[] = {(void*)&h, (void*)&src, (void*)&dst, (void*)&gamma,
                    (void*)&beta, (void*)&W, (void*)&b, (void*)&table,
                    (void*)&out, (void*)&N, (void*)&E};
    hipError_t err = hipLaunchCooperativeKernel((const void*)fused_edge_ln_kernel,
                                                dim3(1024), dim3(256),
                                                args, 0, stream);
    if (err == hipSuccess) return;

    // Fallback: proven two-kernel path (R2).
    int blocks1 = (N + 7) / 8;
    hipLaunchKernelGGL(node_precompute_kernel, dim3(blocks1), dim3(256), 0, stream,
                       h, gamma, beta, W, b, table, consts, N);
    int threads2 = (E + 1) / 2;
    int blocks2 = (threads2 + 255) / 256;
    hipLaunchKernelGGL(edge_score2_kernel, dim3(blocks2), dim3(256), 0, stream,
                       src, dst, table, consts, out, E);
}

// Round 7
// 128.723 us; speedup vs baseline: 3.0136x; 3.0136x over previous
//
#include <hip/hip_runtime.h>

#define LN_EPS 1e-5f

// Sentinel written to per-block done-slots. ws is poisoned to 0xAA bytes
// before every timed launch (harness contract), so slots never start equal
// to the sentinel. Packed-pair compare makes accidental match ~2^-64.
#define DONE_SENT 0x5A17C0DEu
#define DONE_SENT2 0x5A17C0DE5A17C0DEull

// ---------------- Fused single-launch kernel ----------------
// Phase A: per-node table[n]={S,Q,A_lo,A_hi}; 16 lanes/node, 4 nodes/wave
//   (one wave produces one full 64B table line -> no cross-XCD partial lines).
//   Table stored with device-scope (agent) relaxed atomic stores: write-through
//   to the L3 coherence point, NO buffer_wbl2 needed (the R6 killer).
// Barrier: per-block sentinel slot + all-block poll with s_sleep backoff,
//   then one acquire load per block (single buffer_inv) -> L2 clean.
// Phase B: 2 edges/thread grid-stride; first iteration's indices preloaded
//   into registers BEFORE the barrier (overlaps idx streaming with Phase A).
__global__ __launch_bounds__(256, 4)
void fused_edge_ln_kernel(const float* __restrict__ h,
                          const int* __restrict__ src,
                          const int* __restrict__ dst,
                          const float* __restrict__ gamma,
                          const float* __restrict__ beta,
                          const float* __restrict__ W,
                          const float* __restrict__ bias,
                          float4* __restrict__ table,
                          unsigned int* __restrict__ done,
                          float* __restrict__ out,
                          int N, int E)
{
    const int tid  = threadIdx.x;
    const int lane = tid & 63;
    const int q    = lane & 15;   // quarter-lane within node
    const int sub  = lane >> 4;   // node 0..3 within the wave's line

    const float4* g4 = (const float4*)gamma;
    const float4* b4 = (const float4*)beta;
    const float4* w4 = (const float4*)W;

    // Wave-local constants (L1 broadcast loads, once per wave)
    {
    }
    float4 gg = g4[lane], ww = w4[lane], bb = b4[lane];
    float gwsum = (gg.x * ww.x + gg.y * ww.y) + (gg.z * ww.z + gg.w * ww.w);
    float bwsum = (bb.x * ww.x + bb.y * ww.y) + (bb.z * ww.z + bb.w * ww.w);
#pragma unroll
    for (int m = 1; m < 64; m <<= 1) {
        gwsum += __shfl_xor(gwsum, m, 64);
        bwsum += __shfl_xor(bwsum, m, 64);
    }
    const float sum_gw = gwsum;
    const float cbeta  = bwsum + bias[0];
    const float inv_d  = 1.0f / 256.0f;

    // gamma*W fragments for this lane's node-row slices:
    // node row features [4q..4q+3] and [64+4q..64+4q+3]
    float4 ga = g4[q],      wa = w4[q];       // (gW)[4q..]      for A_lo
    float4 gb = g4[q + 16], wb = w4[q + 16];  // (gW)[64+4q..]   for A_lo
    float4 gc = g4[q + 32], wc = w4[q + 32];  // (gW)[128+4q..]  for A_hi
    float4 gd = g4[q + 48], wd = w4[q + 48];  // (gW)[192+4q..]  for A_hi
    float4 cLoA = {ga.x * wa.x, ga.y * wa.y, ga.z * wa.z, ga.w * wa.w};
    float4 cLoB = {gb.x * wb.x, gb.y * wb.y, gb.z * wb.z, gb.w * wb.w};
    float4 cHiA = {gc.x * wc.x, gc.y * wc.y, gc.z * wc.z, gc.w * wc.w};
    float4 cHiB = {gd.x * wd.x, gd.y * wd.y, gd.z * wd.z, gd.w * wd.w};

    // ---- Phase A: node table, 4 consecutive nodes per wave ----
    const int waveId = (blockIdx.x * blockDim.x + tid) >> 6;
    const int nWaves = (gridDim.x * blockDim.x) >> 6;
    const int nGroups = (N + 3) >> 2;

    for (int g = waveId; g < nGroups; g += nWaves) {
        const int node = g * 4 + sub;
        if (node < N) {
            const float4* row = (const float4*)h + (size_t)node * 32;
            float4 va = row[q];
            float4 vb = row[q + 16];

            float s = ((va.x + va.y) + (va.z + va.w))
                    + ((vb.x + vb.y) + (vb.z + vb.w));
            float qq = fmaf(va.x, va.x, fmaf(va.y, va.y, fmaf(va.z, va.z, va.w * va.w)));
            qq = fmaf(vb.x, vb.x, fmaf(vb.y, vb.y, fmaf(vb.z, vb.z, fmaf(vb.w, vb.w, qq))));
            float alo = fmaf(va.x, cLoA.x, fmaf(va.y, cLoA.y, fmaf(va.z, cLoA.z, va.w * cLoA.w)));
            alo = fmaf(vb.x, cLoB.x, fmaf(vb.y, cLoB.y, fmaf(vb.z, cLoB.z, fmaf(vb.w, cLoB.w, alo))));
            float ahi = fmaf(va.x, cHiA.x, fmaf(va.y, cHiA.y, fmaf(va.z, cHiA.z, va.w * cHiA.w)));
            ahi = fmaf(vb.x, cHiB.x, fmaf(vb.y, cHiB.y, fmaf(vb.z, cHiB.z, fmaf(vb.w, cHiB.w, ahi))));

            // 16-lane butterfly (masks 1,2,4,8 stay within the node group)
#pragma unroll
            for (int m = 1; m < 16; m <<= 1) {
                s   += __shfl_xor(s,   m, 64);
                qq  += __shfl_xor(qq,  m, 64);
                alo += __shfl_xor(alo, m, 64);
                ahi += __shfl_xor(ahi, m, 64);
            }
            if (q == 0) {
                // Device-scope (agent) relaxed stores: write-through to L3.
                unsigned long long lo =
                    ((unsigned long long)__float_as_uint(qq) << 32) | __float_as_uint(s);
                unsigned long long hi =
                    ((unsigned long long)__float_as_uint(ahi) << 32) | __float_as_uint(alo);
                unsigned long long* dst64 = (unsigned long long*)(table + node);
                __hip_atomic_store(&dst64[0], lo, __ATOMIC_RELAXED, __HIP_MEMORY_SCOPE_AGENT);
                __hip_atomic_store(&dst64[1], hi, __ATOMIC_RELAXED, __HIP_MEMORY_SCOPE_AGENT);
            }
        }
    }

    // Drain this wave's table stores to the coherence point, then block-sync,
    // then one sentinel store per block.
    __builtin_amdgcn_s_waitcnt(0);
    __syncthreads();
    if (tid == 0) {
        __hip_atomic_store(&done[blockIdx.x], DONE_SENT,
                           __ATOMIC_RELAXED, __HIP_MEMORY_SCOPE_AGENT);
    }

    // Preload first edge-pair indices into registers (overlaps with Phase A
    // of slower blocks; survives the barrier in VGPRs).
    const int t  = blockIdx.x * blockDim.x + tid;
    const int nT = gridDim.x * blockDim.x;
    const int nPairs = E >> 1;
    const int2* src2 = (const int2*)src;
    const int2* dst2 = (const int2*)dst;
    int2 sA = {0, 0}, dA = {0, 0};
    const bool v0 = (t < nPairs);
    if (v0) { sA = src2[t]; dA = dst2[t]; }

    // ---- Barrier: poll all 1024 sentinel slots (thread i -> slots 4i..4i+3) ----
    const unsigned long long* d64 = (const unsigned long long*)done;
    for (;;) {
        unsigned long long a = __hip_atomic_load(&d64[tid * 2],     __ATOMIC_RELAXED, __HIP_MEMORY_SCOPE_AGENT);
        unsigned long long b = __hip_atomic_load(&d64[tid * 2 + 1], __ATOMIC_RELAXED, __HIP_MEMORY_SCOPE_AGENT);
        int ok = (a == DONE_SENT2) && (b == DONE_SENT2);
        if (__syncthreads_count(ok) == 256) break;
        __builtin_amdgcn_s_sleep(32);
    }
    // One acquire (buffer_inv) per block so normal cached loads see the table.
    if (tid == 0) {
        (void)__hip_atomic_load(&d64[0], __ATOMIC_ACQUIRE, __HIP_MEMORY_SCOPE_AGENT);
    }
    __syncthreads();

    // ---- Phase B: edge scoring, 2 edges/thread grid-stride ----
    if (v0) {
        float4 ts0 = table[sA.x];
        float4 td0 = table[dA.x];
        float4 ts1 = table[sA.y];
        float4 td1 = table[dA.y];
        float s0 = ts0.x + td0.x, q0 = ts0.y + td0.y, a0 = ts0.z + td0.w;
        float s1 = ts1.x + td1.x, q1 = ts1.y + td1.y, a1 = ts1.z + td1.w;
        float mu0  = s0 * inv_d;
        float var0 = fmaf(-mu0, mu0, q0 * inv_d);
        float rs0  = rsqrtf(var0 + LN_EPS);
        float mu1  = s1 * inv_d;
        float var1 = fmaf(-mu1, mu1, q1 * inv_d);
        float rs1  = rsqrtf(var1 + LN_EPS);
        float2 r;
        r.x = fmaf(rs0, fmaf(-mu0, sum_gw, a0), cbeta);
        r.y = fmaf(rs1, fmaf(-mu1, sum_gw, a1), cbeta);
        *(float2*)(out + 2 * t) = r;
    }
    for (int p = t + nT; p < nPairs; p += nT) {
        int2 s2 = src2[p];
        int2 d2 = dst2[p];
        float4 ts0 = table[s2.x];
        float4 td0 = table[d2.x];
        float4 ts1 = table[s2.y];
        float4 td1 = table[d2.y];
        float s0 = ts0.x + td0.x, q0 = ts0.y + td0.y, a0 = ts0.z + td0.w;
        float s1 = ts1.x + td1.x, q1 = ts1.y + td1.y, a1 = ts1.z + td1.w;
        float mu0  = s0 * inv_d;
        float var0 = fmaf(-mu0, mu0, q0 * inv_d);
        float rs0  = rsqrtf(var0 + LN_EPS);
        float mu1  = s1 * inv_d;
        float var1 = fmaf(-mu1, mu1, q1 * inv_d);
        float rs1  = rsqrtf(var1 + LN_EPS);
        float2 r;
        r.x = fmaf(rs0, fmaf(-mu0, sum_gw, a0), cbeta);
        r.y = fmaf(rs1, fmaf(-mu1, sum_gw, a1), cbeta);
        *(float2*)(out + 2 * p) = r;
    }
    if ((E & 1) && t == 0) {
        const int e = E - 1;
        float4 ts = table[src[e]];
        float4 td = table[dst[e]];
        float s = ts.x + td.x, qv = ts.y + td.y, a = ts.z + td.w;
        float mu  = s * inv_d;
        float var = fmaf(-mu, mu, qv * inv_d);
        float rs  = rsqrtf(var + LN_EPS);
        out[e] = fmaf(rs, fmaf(-mu, sum_gw, a), cbeta);
    }
}

// ---------------- Two-kernel fallback (R2-proven, 119.7 us) ----------------
__global__ __launch_bounds__(256)
void node_precompute_kernel(const float* __restrict__ h,
                            const float* __restrict__ gamma,
                            const float* __restrict__ beta,
                            const float* __restrict__ W,
                            const float* __restrict__ bias,
                            float4* __restrict__ table,
                            float* __restrict__ consts,
                            int N)
{
    const int tid  = threadIdx.x;
    const int lane = tid & 63;
    const int l    = lane & 31;
    const int half = lane >> 5;

    const float4* g4 = (const float4*)gamma;
    const float4* b4 = (const float4*)beta;
    const float4* w4 = (const float4*)W;

    if (blockIdx.x == 0 && tid < 64) {
        float4 gg = g4[tid], ww = w4[tid], bb = b4[tid];
        float gwsum = (gg.x * ww.x + gg.y * ww.y) + (gg.z * ww.z + gg.w * ww.w);
        float bwsum = (bb.x * ww.x + bb.y * ww.y) + (bb.z * ww.z + bb.w * ww.w);
#pragma unroll
        for (int m = 1; m < 64; m <<= 1) {
            gwsum += __shfl_xor(gwsum, m, 64);
            bwsum += __shfl_xor(bwsum, m, 64);
        }
        if (tid == 0) { consts[0] = gwsum; consts[1] = bwsum + bias[0]; }
    }

    float4 glo = g4[l],      wlo = w4[l];
    float4 ghi = g4[l + 32], whi = w4[l + 32];
    float4 gwlo = {glo.x * wlo.x, glo.y * wlo.y, glo.z * wlo.z, glo.w * wlo.w};
    float4 gwhi = {ghi.x * whi.x, ghi.y * whi.y, ghi.z * whi.z, ghi.w * whi.w};

    const int waveInBlock = tid >> 6;
    const int node = (blockIdx.x * 4 + waveInBlock) * 2 + half;
    if (node >= N) return;

    const float4* row = (const float4*)h + (size_t)node * 32;
    float4 v = row[l];

    float s = (v.x + v.y) + (v.z + v.w);
    float q = fmaf(v.x, v.x, fmaf(v.y, v.y, fmaf(v.z, v.z, v.w * v.w)));
    float alo = fmaf(v.x, gwlo.x, fmaf(v.y, gwlo.y, fmaf(v.z, gwlo.z, v.w * gwlo.w)));
    float ahi = fmaf(v.x, gwhi.x, fmaf(v.y, gwhi.y, fmaf(v.z, gwhi.z, v.w * gwhi.w)));

#pragma unroll
    for (int m = 1; m < 32; m <<= 1) {
        s   += __shfl_xor(s,   m, 64);
        q   += __shfl_xor(q,   m, 64);
        alo += __shfl_xor(alo, m, 64);
        ahi += __shfl_xor(ahi, m, 64);
    }
    if (l == 0) table[node] = make_float4(s, q, alo, ahi);
}

__global__ __launch_bounds__(256)
void edge_score2_kernel(const int* __restrict__ src,
                        const int* __restrict__ dst,
                        const float4* __restrict__ table,
                        const float* __restrict__ consts,
                        float* __restrict__ out,
                        int E)
{
    const int t = blockIdx.x * blockDim.x + threadIdx.x;
    const int e0 = t * 2;
    if (e0 >= E) return;

    const float sum_gw = consts[0];
    const float cbeta  = consts[1];
    const float inv_d  = 1.0f / 256.0f;

    if (e0 + 1 < E) {
        int2 s2 = *(const int2*)(src + e0);
        int2 d2 = *(const int2*)(dst + e0);
        float4 ts0 = table[s2.x];
        float4 td0 = table[d2.x];
        float4 ts1 = table[s2.y];
        float4 td1 = table[d2.y];

        float s0 = ts0.x + td0.x, q0 = ts0.y + td0.y, a0 = ts0.z + td0.w;
        float s1 = ts1.x + td1.x, q1 = ts1.y + td1.y, a1 = ts1.z + td1.w;

        float mu0  = s0 * inv_d;
        float var0 = fmaf(-mu0, mu0, q0 * inv_d);
        float rs0  = rsqrtf(var0 + LN_EPS);
        float mu1  = s1 * inv_d;
        float var1 = fmaf(-mu1, mu1, q1 * inv_d);
        float rs1  = rsqrtf(var1 + LN_EPS);

        float2 r;
        r.x = fmaf(rs0, fmaf(-mu0, sum_gw, a0), cbeta);
        r.y = fmaf(rs1, fmaf(-mu1, sum_gw, a1), cbeta);
        *(float2*)(out + e0) = r;
    } else {
        float4 ts = table[src[e0]];
        float4 td = table[dst[e0]];
        float s = ts.x + td.x;
        float q = ts.y + td.y;
        float a = ts.z + td.w;
        float mu  = s * inv_d;
        float var = fmaf(-mu, mu, q * inv_d);
        float rs  = rsqrtf(var + LN_EPS);
        out[e0] = fmaf(rs, fmaf(-mu, sum_gw, a), cbeta);
    }
}

extern "C" void kernel_launch(void* const* d_in, const int* in_sizes, int n_in,
                              void* d_out, int out_size, void* d_ws, size_t ws_size,
                              hipStream_t stream) {
    const float* h     = (const float*)d_in[0];
    const int*   src   = (const int*)d_in[1];
    const int*   dst   = (const int*)d_in[2];
    const float* gamma = (const float*)d_in[3];
    const float* beta  = (const float*)d_in[4];
    const float* W     = (const float*)d_in[5];
    const float* b     = (const float*)d_in[6];
    float* out = (float*)d_out;
    const int E = in_sizes[1];
    const int N = in_sizes[0] / 128;

    float4*       table = (float4*)d_ws;
    unsigned int* done  = (unsigned int*)((char*)d_ws + (size_t)N * 16);
    float*        consts = (float*)((char*)d_ws + (size_t)N * 16 + 4096);

    const size_t ws_needed = (size_t)N * 16 + 4096 + 64;
    if (ws_size >= ws_needed) {
        // Fused single-launch path: 1024 blocks x 256 thr, guaranteed
        // co-resident (4 blocks/CU at <=128 VGPR) -> safe sw barrier.
        hipLaunchKernelGGL(fused_edge_ln_kernel, dim3(1024), dim3(256), 0, stream,
                           h, src, dst, gamma, beta, W, b, table, done, out, N, E);
        return;
    }

    // Fallback: proven two-kernel path (R2).
    int blocks1 = (N + 7) / 8;
    hipLaunchKernelGGL(node_precompute_kernel, dim3(blocks1), dim3(256), 0, stream,
                       h, gamma, beta, W, b, table, consts, N);
    int threads2 = (E + 1) / 2;
    int blocks2 = (threads2 + 255) / 256;
    hipLaunchKernelGGL(edge_score2_kernel, dim3(blocks2), dim3(256), 0, stream,
                       src, dst, table, consts, out, E);
}